// Round 5
// baseline (367.512 us; speedup 1.0000x reference)
//
#include <hip/hip_runtime.h>

// Problem constants (from reference setup_inputs)
#define BB 2048
#define TT 16
#define RR 2048
#define NPAIR (TT - 1)
#define NCLS 64            // class_loss blocks

// ws layout (floats):
//   [0..63]      clsPartB  (per-block bce*vm partial sums)
//   [64..127]    clsPartV  (per-block vm partial sums)
//   [128..]      smoothPart[4096][8]  (per-block raw pair sums; /R folded later)
// No atomics, no memset: every slot read by final_kernel is written every call.

__device__ __forceinline__ float log_sigmoid(float x) {
    return fminf(x, 0.0f) - log1pf(expf(-fabsf(x)));
}

// ---------------------------------------------------------------------------
// Kernel A: BCE partials, one (bce,vm) pair per block, plain stores.
// ---------------------------------------------------------------------------
__global__ void class_loss_kernel(const float* __restrict__ pred,
                                  const int* __restrict__ targets,
                                  const int* __restrict__ vm,
                                  float* __restrict__ ws) {
    int tid = blockIdx.x * blockDim.x + threadIdx.x;
    int stride = gridDim.x * blockDim.x;
    float bce_sum = 0.f, vm_sum = 0.f;
    for (int i = tid; i < BB * TT; i += stride) {
        float x = pred[i];
        float y = (float)targets[i];
        float v = (float)vm[i];
        float bce = -(2.0f * y * log_sigmoid(x) + (1.0f - y) * log_sigmoid(-x));
        bce_sum += bce * v;
        vm_sum += v;
    }
    #pragma unroll
    for (int off = 32; off; off >>= 1) {
        bce_sum += __shfl_down(bce_sum, off);
        vm_sum  += __shfl_down(vm_sum, off);
    }
    __shared__ float s_b[4], s_v[4];
    int lane = threadIdx.x & 63, wave = threadIdx.x >> 6;
    if (lane == 0) { s_b[wave] = bce_sum; s_v[wave] = vm_sum; }
    __syncthreads();
    if (threadIdx.x == 0) {
        float b = 0.f, v = 0.f;
        int nw = blockDim.x >> 6;
        for (int w = 0; w < nw; ++w) { b += s_b[w]; v += s_v[w]; }
        ws[blockIdx.x] = b;          // clsPartB
        ws[NCLS + blockIdx.x] = v;   // clsPartV
    }
}

// ---------------------------------------------------------------------------
// Kernel B: smoothness partials. Grid = 2048 b x 2 halves, 512 threads.
// Half h=0: slices t=0..8, pairs 0..7.  h=1: slices t=8..15, pairs 8..14.
// Gated float4 loads (block-uniform predicates), per-block partials stored
// unconditionally to part[blk][8] (slot 7 of h=1 blocks is always 0).
// ---------------------------------------------------------------------------
__global__ __launch_bounds__(512)
void smooth_kernel(const float* __restrict__ rs,
                   const int* __restrict__ vm,
                   float* __restrict__ part) {
    const int b = blockIdx.x >> 1;
    const int h = blockIdx.x & 1;
    const int t0 = h * 8;
    const int np = h ? 7 : 8;

    __shared__ int s_vm[TT];
    if (threadIdx.x < TT) s_vm[threadIdx.x] = vm[b * TT + threadIdx.x];
    __syncthreads();

    bool pv[8];
    #pragma unroll
    for (int i = 0; i < 8; ++i) {
        int gp = t0 + i;
        pv[i] = (i < np) && (s_vm[gp] != 0) && (s_vm[gp + 1] != 0);
    }

    const float4* base = (const float4*)(rs + (size_t)b * TT * RR);
    const int r4 = threadIdx.x;  // 0..511 covers R/4 = 512

    // Slice i needed iff an adjacent handled pair is valid.
    // i=8 only exists for h=0 (pv[7] is false when h=1 since np=7).
    float4 sl[9];
    #pragma unroll
    for (int i = 0; i < 9; ++i) {
        bool need = (i == 0) ? pv[0] : (i == 8) ? pv[7] : (pv[i - 1] || pv[i]);
        if (need) sl[i] = base[(t0 + i) * (RR / 4) + r4];
        else      sl[i] = make_float4(0.f, 0.f, 0.f, 0.f);
    }

    float acc[8];
    #pragma unroll
    for (int p = 0; p < 8; ++p) {
        acc[p] = 0.f;
        if (pv[p]) {
            float dx = fmaxf(fabsf(sl[p + 1].x - sl[p].x) - 0.2f, 0.f);
            float dy = fmaxf(fabsf(sl[p + 1].y - sl[p].y) - 0.2f, 0.f);
            float dz = fmaxf(fabsf(sl[p + 1].z - sl[p].z) - 0.2f, 0.f);
            float dw = fmaxf(fabsf(sl[p + 1].w - sl[p].w) - 0.2f, 0.f);
            acc[p] = dx * dx + dy * dy + dz * dz + dw * dw;
        }
    }

    __shared__ float s_acc[8][8];
    int lane = threadIdx.x & 63, wave = threadIdx.x >> 6;
    #pragma unroll
    for (int p = 0; p < 8; ++p) {
        if (pv[p]) {
            float v = acc[p];
            #pragma unroll
            for (int off = 32; off; off >>= 1) v += __shfl_down(v, off);
            if (lane == 0) s_acc[wave][p] = v;
        }
    }
    __syncthreads();
    if (threadIdx.x < 8) {
        int p = threadIdx.x;
        float s = 0.f;
        if (pv[p]) {
            #pragma unroll
            for (int w = 0; w < 8; ++w) s += s_acc[w][p];
        }
        part[(size_t)blockIdx.x * 8 + p] = s;  // unconditional (overwrites poison)
    }
}

// ---------------------------------------------------------------------------
// Kernel C: final reduce + exact reference reduction order. 1 block, 16 waves.
// Waves 0..14: pair p — sum part over b, count valid pairs from vm.
// Wave 15: class partials.
// ---------------------------------------------------------------------------
__global__ __launch_bounds__(1024)
void final_kernel(const float* __restrict__ ws,
                  const int* __restrict__ vm,
                  float* __restrict__ out) {
    const float* part = ws + 2 * NCLS;
    int lane = threadIdx.x & 63, wave = threadIdx.x >> 6;

    __shared__ float s_S[NPAIR];
    __shared__ int   s_cnt[NPAIR];
    __shared__ float s_cls[2];

    if (wave < NPAIR) {
        int p = wave;
        int h = (p < 8) ? 0 : 1;
        int i = p - h * 8;
        float s = 0.f;
        int cnt = 0;
        for (int b = lane; b < BB; b += 64) {
            s += part[(size_t)(2 * b + h) * 8 + i];
            cnt += (vm[b * TT + p] != 0 && vm[b * TT + p + 1] != 0) ? 1 : 0;
        }
        #pragma unroll
        for (int off = 32; off; off >>= 1) {
            s += __shfl_down(s, off);
            cnt += __shfl_down(cnt, off);
        }
        if (lane == 0) { s_S[p] = s; s_cnt[p] = cnt; }
    } else if (wave == 15) {
        float b = (lane < NCLS) ? ws[lane] : 0.f;
        float v = (lane < NCLS) ? ws[NCLS + lane] : 0.f;
        #pragma unroll
        for (int off = 32; off; off >>= 1) {
            b += __shfl_down(b, off);
            v += __shfl_down(v, off);
        }
        if (lane == 0) { s_cls[0] = b; s_cls[1] = v; }
    }
    __syncthreads();

    if (threadIdx.x == 0) {
        float class_loss = s_cls[0] / fmaxf(s_cls[1], 1e-8f);
        float step_sum = 0.f;
        int num_steps = 0;
        for (int p = 0; p < NPAIR; ++p) {
            int c = s_cnt[p];
            float pen_sum = s_S[p] / (float)RR;  // region mean folded in
            step_sum += pen_sum / (float)(c > 0 ? c : 1);
            if (c > 0) ++num_steps;
        }
        float smooth = (num_steps > 0) ? (step_sum / (float)num_steps) : 0.f;
        out[0] = class_loss + 0.2f * smooth;
    }
}

extern "C" void kernel_launch(void* const* d_in, const int* in_sizes, int n_in,
                              void* d_out, int out_size, void* d_ws, size_t ws_size,
                              hipStream_t stream) {
    const float* pred    = (const float*)d_in[0];  // [B,T,1] f32
    const float* rs      = (const float*)d_in[1];  // [B,T,R,1] f32
    const int*   targets = (const int*)d_in[2];    // [B,T] i32
    const int*   vmask   = (const int*)d_in[3];    // [B,T] i32
    float* out = (float*)d_out;
    float* ws  = (float*)d_ws;

    class_loss_kernel<<<NCLS, 256, 0, stream>>>(pred, targets, vmask, ws);
    smooth_kernel<<<BB * 2, 512, 0, stream>>>(rs, vmask, ws + 2 * NCLS);
    final_kernel<<<1, 1024, 0, stream>>>(ws, vmask, out);
}